// Round 5
// baseline (149.829 us; speedup 1.0000x reference)
//
#include <hip/hip_runtime.h>

#define NUM_ENT 7
#define DIM_ENT 4
#define H 128            // NEMBED_HALF
#define OUTC (2 * H)     // 256 columns per entity
#define BPB 16           // batch elements per block

// Grid = 2*(B/BPB) blocks of 256 threads, roles INTERLEAVED for tail balance:
//   even blocks: REL  — rel_emb  (cols 128..255) for 16 batch elems.
//   odd  blocks: PROP — prop_emb (cols 0..127)   for 16 batch elems.
// Half-wave hw = tid>>5 (0..7) serves batch elems {2*hw, 2*hw+1};
// c4 = (lane&31)*4 is the column group. No intra-wave divergence
// (s_feat/s_ents reads are 2-way broadcast across half-waves — free).
__global__ __launch_bounds__(256) void ace_kernel(
    const float* __restrict__ ctx,     // [28, B]
    const float* __restrict__ w_prop,  // [4, 128]
    const float* __restrict__ b_prop,  // [128]
    const float* __restrict__ w_rel,   // [5, 128]
    const float* __restrict__ b_rel,   // [128]
    float* __restrict__ out,           // [B, 7, 256]
    int B)
{
    __shared__ float s_ents[BPB][NUM_ENT * DIM_ENT];          // 16 x 28
    __shared__ float s_feat[BPB][NUM_ENT][NUM_ENT][5];        // 16 x 49 x 5

    const int tid = threadIdx.x;
    const bool is_rel = (blockIdx.x & 1) == 0;
    const int blk = blockIdx.x >> 1;
    const int b0 = blk * BPB;

    // Stage ents, b-fastest for coalescing: t -> (k = t>>4, bb = t&15)
#pragma unroll
    for (int t = tid; t < BPB * NUM_ENT * DIM_ENT; t += 256) {   // 448
        const int k  = t >> 4;
        const int bb = t & 15;
        s_ents[bb][k] = ctx[(size_t)k * B + (b0 + bb)];
    }
    __syncthreads();

    if (is_rel) {
        // Precompute pairwise features once per (b,i,j)
        for (int t = tid; t < BPB * NUM_ENT * NUM_ENT; t += 256) {  // 784
            const int bb = t / (NUM_ENT * NUM_ENT);
            const int p  = t % (NUM_ENT * NUM_ENT);
            const int i  = p / NUM_ENT;
            const int j  = p % NUM_ENT;
            const float dx = s_ents[bb][i * 4 + 0] - s_ents[bb][j * 4 + 0];
            const float dy = s_ents[bb][i * 4 + 1] - s_ents[bb][j * 4 + 1];
            const float dz = s_ents[bb][i * 4 + 2] - s_ents[bb][j * 4 + 2];
            const float dw = s_ents[bb][i * 4 + 3] - s_ents[bb][j * 4 + 3];
            s_feat[bb][i][j][0] = dx;
            s_feat[bb][i][j][1] = dy;
            s_feat[bb][i][j][2] = dz;
            s_feat[bb][i][j][3] = dw;
            s_feat[bb][i][j][4] = sqrtf(dx * dx + dy * dy);
        }
        __syncthreads();
    }

    const int lane = tid & 63;
    const int hw   = tid >> 5;            // half-wave id, 0..7
    const int c4   = (lane & 31) << 2;    // column group within the half

    if (is_rel) {
        // rel_emb: sum_{j!=i} relu(feat(i,j) @ w_rel + b_rel) -> cols 128+c4
        const float4 w0 = *(const float4*)(w_rel + 0 * H + c4);
        const float4 w1 = *(const float4*)(w_rel + 1 * H + c4);
        const float4 w2 = *(const float4*)(w_rel + 2 * H + c4);
        const float4 w3 = *(const float4*)(w_rel + 3 * H + c4);
        const float4 w4 = *(const float4*)(w_rel + 4 * H + c4);
        const float4 br = *(const float4*)(b_rel + c4);
#pragma unroll
        for (int r = 0; r < 2; ++r) {
            const int bb = hw * 2 + r;
            float* outb = out + (size_t)(b0 + bb) * (NUM_ENT * OUTC);
#pragma unroll
            for (int i = 0; i < NUM_ENT; ++i) {
                float4 acc = {0.f, 0.f, 0.f, 0.f};
#pragma unroll
                for (int j = 0; j < NUM_ENT; ++j) {
                    if (j == i) continue;
                    const float f0 = s_feat[bb][i][j][0];
                    const float f1 = s_feat[bb][i][j][1];
                    const float f2 = s_feat[bb][i][j][2];
                    const float f3 = s_feat[bb][i][j][3];
                    const float f4 = s_feat[bb][i][j][4];
                    acc.x += fmaxf(br.x + f0 * w0.x + f1 * w1.x + f2 * w2.x + f3 * w3.x + f4 * w4.x, 0.f);
                    acc.y += fmaxf(br.y + f0 * w0.y + f1 * w1.y + f2 * w2.y + f3 * w3.y + f4 * w4.y, 0.f);
                    acc.z += fmaxf(br.z + f0 * w0.z + f1 * w1.z + f2 * w2.z + f3 * w3.z + f4 * w4.z, 0.f);
                    acc.w += fmaxf(br.w + f0 * w0.w + f1 * w1.w + f2 * w2.w + f3 * w3.w + f4 * w4.w, 0.f);
                }
                *(float4*)(outb + i * OUTC + H + c4) = acc;
            }
        }
    } else {
        // prop_emb: relu(ents @ w_prop + b_prop) -> cols c4
        const float4 w0 = *(const float4*)(w_prop + 0 * H + c4);
        const float4 w1 = *(const float4*)(w_prop + 1 * H + c4);
        const float4 w2 = *(const float4*)(w_prop + 2 * H + c4);
        const float4 w3 = *(const float4*)(w_prop + 3 * H + c4);
        const float4 bp = *(const float4*)(b_prop + c4);
#pragma unroll
        for (int r = 0; r < 2; ++r) {
            const int bb = hw * 2 + r;
            float* outb = out + (size_t)(b0 + bb) * (NUM_ENT * OUTC);
#pragma unroll
            for (int n = 0; n < NUM_ENT; ++n) {
                const float e0 = s_ents[bb][n * 4 + 0];
                const float e1 = s_ents[bb][n * 4 + 1];
                const float e2 = s_ents[bb][n * 4 + 2];
                const float e3 = s_ents[bb][n * 4 + 3];
                float4 a;
                a.x = fmaxf(bp.x + e0 * w0.x + e1 * w1.x + e2 * w2.x + e3 * w3.x, 0.f);
                a.y = fmaxf(bp.y + e0 * w0.y + e1 * w1.y + e2 * w2.y + e3 * w3.y, 0.f);
                a.z = fmaxf(bp.z + e0 * w0.z + e1 * w1.z + e2 * w2.z + e3 * w3.z, 0.f);
                a.w = fmaxf(bp.w + e0 * w0.w + e1 * w1.w + e2 * w2.w + e3 * w3.w, 0.f);
                *(float4*)(outb + n * OUTC + c4) = a;
            }
        }
    }
}

extern "C" void kernel_launch(void* const* d_in, const int* in_sizes, int n_in,
                              void* d_out, int out_size, void* d_ws, size_t ws_size,
                              hipStream_t stream) {
    const float* ctx    = (const float*)d_in[0];
    const float* w_prop = (const float*)d_in[1];
    const float* b_prop = (const float*)d_in[2];
    const float* w_rel  = (const float*)d_in[3];
    const float* b_rel  = (const float*)d_in[4];
    float* out = (float*)d_out;

    const int B = in_sizes[0] / (NUM_ENT * DIM_ENT);   // 16384
    const int nb = (B + BPB - 1) / BPB;                // 1024 blocks per role
    ace_kernel<<<2 * nb, 256, 0, stream>>>(ctx, w_prop, b_prop, w_rel, b_rel, out, B);
}

// Round 6
// 135.805 us; speedup vs baseline: 1.1033x; 1.1033x over previous
//
#include <hip/hip_runtime.h>

#define NUM_ENT 7
#define DIM_ENT 4
#define H 128            // NEMBED_HALF
#define OUTC (2 * H)     // 256 columns per entity
#define BPB 8            // batch elements per block

// Grid = 2*ceil(B/BPB) blocks of 256 threads.
// Blocks [0, nb)      : REL  — rel_emb  (cols 128..255) for 8 batch elems.
// Blocks [nb, 2*nb)   : PROP — prop_emb (cols 0..127)   for 8 batch elems.
// NOTE: roles must occupy contiguous blockIdx ranges — an interleaved
// (blockIdx&1) split aliases with the round-robin workgroup->XCD parity and
// concentrates all heavy rel blocks on half the XCDs (R5: +15us regression).
// Within a block: wave w (0..3), lane l: bb = w*2 + (l>>5), c4 = (l&31)*4.
// Both half-waves run IDENTICAL code (different batch element) — no divergence.
__global__ __launch_bounds__(256) void ace_kernel(
    const float* __restrict__ ctx,     // [28, B]
    const float* __restrict__ w_prop,  // [4, 128]
    const float* __restrict__ b_prop,  // [128]
    const float* __restrict__ w_rel,   // [5, 128]
    const float* __restrict__ b_rel,   // [128]
    float* __restrict__ out,           // [B, 7, 256]
    int B)
{
    __shared__ float s_ents[BPB][NUM_ENT * DIM_ENT];          // 8 x 28
    __shared__ float s_feat[BPB][NUM_ENT][NUM_ENT][5];        // 8 x 49 x 5

    const int tid = threadIdx.x;
    const int nb = gridDim.x >> 1;
    const bool is_rel = blockIdx.x < nb;
    const int blk = is_rel ? blockIdx.x : (blockIdx.x - nb);
    const int b0 = blk * BPB;

    // Stage ents, b-fastest for coalescing: tid -> (k = tid>>3, bb = tid&7)
    if (tid < BPB * NUM_ENT * DIM_ENT) {                      // 224 threads
        const int k  = tid >> 3;
        const int bb = tid & 7;
        s_ents[bb][k] = ctx[(size_t)k * B + (b0 + bb)];
    }
    __syncthreads();

    if (is_rel) {
        // Precompute pairwise features once per (b,i,j)
        for (int t = tid; t < BPB * NUM_ENT * NUM_ENT; t += 256) {  // 392
            const int bb = t / (NUM_ENT * NUM_ENT);
            const int p  = t % (NUM_ENT * NUM_ENT);
            const int i  = p / NUM_ENT;
            const int j  = p % NUM_ENT;
            const float dx = s_ents[bb][i * 4 + 0] - s_ents[bb][j * 4 + 0];
            const float dy = s_ents[bb][i * 4 + 1] - s_ents[bb][j * 4 + 1];
            const float dz = s_ents[bb][i * 4 + 2] - s_ents[bb][j * 4 + 2];
            const float dw = s_ents[bb][i * 4 + 3] - s_ents[bb][j * 4 + 3];
            s_feat[bb][i][j][0] = dx;
            s_feat[bb][i][j][1] = dy;
            s_feat[bb][i][j][2] = dz;
            s_feat[bb][i][j][3] = dw;
            s_feat[bb][i][j][4] = sqrtf(dx * dx + dy * dy);
        }
        __syncthreads();
    }

    const int w    = tid >> 6;
    const int lane = tid & 63;
    const int bb   = w * 2 + (lane >> 5);
    const int c4   = (lane & 31) << 2;
    float* outb = out + (size_t)(b0 + bb) * (NUM_ENT * OUTC);

    if (is_rel) {
        // rel_emb: sum_{j!=i} relu(feat(i,j) @ w_rel + b_rel) -> cols 128+c4
        const float4 w0 = *(const float4*)(w_rel + 0 * H + c4);
        const float4 w1 = *(const float4*)(w_rel + 1 * H + c4);
        const float4 w2 = *(const float4*)(w_rel + 2 * H + c4);
        const float4 w3 = *(const float4*)(w_rel + 3 * H + c4);
        const float4 w4 = *(const float4*)(w_rel + 4 * H + c4);
        const float4 br = *(const float4*)(b_rel + c4);
#pragma unroll
        for (int i = 0; i < NUM_ENT; ++i) {
            float4 acc = {0.f, 0.f, 0.f, 0.f};
#pragma unroll
            for (int j = 0; j < NUM_ENT; ++j) {
                if (j == i) continue;
                const float f0 = s_feat[bb][i][j][0];
                const float f1 = s_feat[bb][i][j][1];
                const float f2 = s_feat[bb][i][j][2];
                const float f3 = s_feat[bb][i][j][3];
                const float f4 = s_feat[bb][i][j][4];
                acc.x += fmaxf(br.x + f0 * w0.x + f1 * w1.x + f2 * w2.x + f3 * w3.x + f4 * w4.x, 0.f);
                acc.y += fmaxf(br.y + f0 * w0.y + f1 * w1.y + f2 * w2.y + f3 * w3.y + f4 * w4.y, 0.f);
                acc.z += fmaxf(br.z + f0 * w0.z + f1 * w1.z + f2 * w2.z + f3 * w3.z + f4 * w4.z, 0.f);
                acc.w += fmaxf(br.w + f0 * w0.w + f1 * w1.w + f2 * w2.w + f3 * w3.w + f4 * w4.w, 0.f);
            }
            *(float4*)(outb + i * OUTC + H + c4) = acc;
        }
    } else {
        // prop_emb: relu(ents @ w_prop + b_prop) -> cols c4
        const float4 w0 = *(const float4*)(w_prop + 0 * H + c4);
        const float4 w1 = *(const float4*)(w_prop + 1 * H + c4);
        const float4 w2 = *(const float4*)(w_prop + 2 * H + c4);
        const float4 w3 = *(const float4*)(w_prop + 3 * H + c4);
        const float4 bp = *(const float4*)(b_prop + c4);
#pragma unroll
        for (int n = 0; n < NUM_ENT; ++n) {
            const float e0 = s_ents[bb][n * 4 + 0];
            const float e1 = s_ents[bb][n * 4 + 1];
            const float e2 = s_ents[bb][n * 4 + 2];
            const float e3 = s_ents[bb][n * 4 + 3];
            float4 a;
            a.x = fmaxf(bp.x + e0 * w0.x + e1 * w1.x + e2 * w2.x + e3 * w3.x, 0.f);
            a.y = fmaxf(bp.y + e0 * w0.y + e1 * w1.y + e2 * w2.y + e3 * w3.y, 0.f);
            a.z = fmaxf(bp.z + e0 * w0.z + e1 * w1.z + e2 * w2.z + e3 * w3.z, 0.f);
            a.w = fmaxf(bp.w + e0 * w0.w + e1 * w1.w + e2 * w2.w + e3 * w3.w, 0.f);
            *(float4*)(outb + n * OUTC + c4) = a;
        }
    }
}

extern "C" void kernel_launch(void* const* d_in, const int* in_sizes, int n_in,
                              void* d_out, int out_size, void* d_ws, size_t ws_size,
                              hipStream_t stream) {
    const float* ctx    = (const float*)d_in[0];
    const float* w_prop = (const float*)d_in[1];
    const float* b_prop = (const float*)d_in[2];
    const float* w_rel  = (const float*)d_in[3];
    const float* b_rel  = (const float*)d_in[4];
    float* out = (float*)d_out;

    const int B = in_sizes[0] / (NUM_ENT * DIM_ENT);   // 16384
    const int nb = (B + BPB - 1) / BPB;                // 2048 blocks per role
    ace_kernel<<<2 * nb, 256, 0, stream>>>(ctx, w_prop, b_prop, w_rel, b_rel, out, B);
}

// Round 7
// 133.633 us; speedup vs baseline: 1.1212x; 1.0163x over previous
//
#include <hip/hip_runtime.h>

#define NUM_ENT 7
#define DIM_ENT 4
#define H 128            // NEMBED_HALF
#define OUTC (2 * H)     // 256 columns per entity
#define BPB 8            // batch elements per block

// Grid = B/BPB = 2048 blocks of 256 threads. Each block computes BOTH the
// rel_emb (cols 128..255) and prop_emb (cols 0..127) for its 8 batch elems:
// ctx staged once, one set of syncs, fully contiguous 57 KiB output region
// per block. (R5 lesson: do NOT parity-split roles across blockIdx — it
// aliases with round-robin workgroup->XCD assignment; merging avoids the
// question entirely.)
// Within a block: wave w (0..3), lane l: bb = w*2 + (l>>5), c4 = (l&31)*4.
// Both half-waves run IDENTICAL code (different batch element) — no divergence.
__global__ __launch_bounds__(256) void ace_kernel(
    const float* __restrict__ ctx,     // [28, B]
    const float* __restrict__ w_prop,  // [4, 128]
    const float* __restrict__ b_prop,  // [128]
    const float* __restrict__ w_rel,   // [5, 128]
    const float* __restrict__ b_rel,   // [128]
    float* __restrict__ out,           // [B, 7, 256]
    int B)
{
    __shared__ float s_ents[BPB][NUM_ENT * DIM_ENT];          // 8 x 28
    __shared__ float s_feat[BPB][NUM_ENT][NUM_ENT][5];        // 8 x 49 x 5

    const int tid = threadIdx.x;
    const int b0 = blockIdx.x * BPB;

    // Stage ents, b-fastest for coalescing: tid -> (k = tid>>3, bb = tid&7)
    if (tid < BPB * NUM_ENT * DIM_ENT) {                      // 224 threads
        const int k  = tid >> 3;
        const int bb = tid & 7;
        s_ents[bb][k] = ctx[(size_t)k * B + (b0 + bb)];
    }
    __syncthreads();

    // Precompute pairwise features once per (b,i,j)
    for (int t = tid; t < BPB * NUM_ENT * NUM_ENT; t += 256) {  // 392
        const int bb = t / (NUM_ENT * NUM_ENT);
        const int p  = t % (NUM_ENT * NUM_ENT);
        const int i  = p / NUM_ENT;
        const int j  = p % NUM_ENT;
        const float dx = s_ents[bb][i * 4 + 0] - s_ents[bb][j * 4 + 0];
        const float dy = s_ents[bb][i * 4 + 1] - s_ents[bb][j * 4 + 1];
        const float dz = s_ents[bb][i * 4 + 2] - s_ents[bb][j * 4 + 2];
        const float dw = s_ents[bb][i * 4 + 3] - s_ents[bb][j * 4 + 3];
        s_feat[bb][i][j][0] = dx;
        s_feat[bb][i][j][1] = dy;
        s_feat[bb][i][j][2] = dz;
        s_feat[bb][i][j][3] = dw;
        s_feat[bb][i][j][4] = sqrtf(dx * dx + dy * dy);
    }
    __syncthreads();

    const int w    = tid >> 6;
    const int lane = tid & 63;
    const int bb   = w * 2 + (lane >> 5);
    const int c4   = (lane & 31) << 2;
    float* outb = out + (size_t)(b0 + bb) * (NUM_ENT * OUTC);

    {   // ---- rel_emb: sum_{j!=i} relu(feat(i,j) @ w_rel + b_rel) -> cols 128+c4
        const float4 w0 = *(const float4*)(w_rel + 0 * H + c4);
        const float4 w1 = *(const float4*)(w_rel + 1 * H + c4);
        const float4 w2 = *(const float4*)(w_rel + 2 * H + c4);
        const float4 w3 = *(const float4*)(w_rel + 3 * H + c4);
        const float4 w4 = *(const float4*)(w_rel + 4 * H + c4);
        const float4 br = *(const float4*)(b_rel + c4);
#pragma unroll
        for (int i = 0; i < NUM_ENT; ++i) {
            float4 acc = {0.f, 0.f, 0.f, 0.f};
#pragma unroll
            for (int j = 0; j < NUM_ENT; ++j) {
                if (j == i) continue;
                const float f0 = s_feat[bb][i][j][0];
                const float f1 = s_feat[bb][i][j][1];
                const float f2 = s_feat[bb][i][j][2];
                const float f3 = s_feat[bb][i][j][3];
                const float f4 = s_feat[bb][i][j][4];
                acc.x += fmaxf(br.x + f0 * w0.x + f1 * w1.x + f2 * w2.x + f3 * w3.x + f4 * w4.x, 0.f);
                acc.y += fmaxf(br.y + f0 * w0.y + f1 * w1.y + f2 * w2.y + f3 * w3.y + f4 * w4.y, 0.f);
                acc.z += fmaxf(br.z + f0 * w0.z + f1 * w1.z + f2 * w2.z + f3 * w3.z + f4 * w4.z, 0.f);
                acc.w += fmaxf(br.w + f0 * w0.w + f1 * w1.w + f2 * w2.w + f3 * w3.w + f4 * w4.w, 0.f);
            }
            *(float4*)(outb + i * OUTC + H + c4) = acc;
        }
    }

    {   // ---- prop_emb: relu(ents @ w_prop + b_prop) -> cols c4
        const float4 w0 = *(const float4*)(w_prop + 0 * H + c4);
        const float4 w1 = *(const float4*)(w_prop + 1 * H + c4);
        const float4 w2 = *(const float4*)(w_prop + 2 * H + c4);
        const float4 w3 = *(const float4*)(w_prop + 3 * H + c4);
        const float4 bp = *(const float4*)(b_prop + c4);
#pragma unroll
        for (int n = 0; n < NUM_ENT; ++n) {
            const float e0 = s_ents[bb][n * 4 + 0];
            const float e1 = s_ents[bb][n * 4 + 1];
            const float e2 = s_ents[bb][n * 4 + 2];
            const float e3 = s_ents[bb][n * 4 + 3];
            float4 a;
            a.x = fmaxf(bp.x + e0 * w0.x + e1 * w1.x + e2 * w2.x + e3 * w3.x, 0.f);
            a.y = fmaxf(bp.y + e0 * w0.y + e1 * w1.y + e2 * w2.y + e3 * w3.y, 0.f);
            a.z = fmaxf(bp.z + e0 * w0.z + e1 * w1.z + e2 * w2.z + e3 * w3.z, 0.f);
            a.w = fmaxf(bp.w + e0 * w0.w + e1 * w1.w + e2 * w2.w + e3 * w3.w, 0.f);
            *(float4*)(outb + n * OUTC + c4) = a;
        }
    }
}

extern "C" void kernel_launch(void* const* d_in, const int* in_sizes, int n_in,
                              void* d_out, int out_size, void* d_ws, size_t ws_size,
                              hipStream_t stream) {
    const float* ctx    = (const float*)d_in[0];
    const float* w_prop = (const float*)d_in[1];
    const float* b_prop = (const float*)d_in[2];
    const float* w_rel  = (const float*)d_in[3];
    const float* b_rel  = (const float*)d_in[4];
    float* out = (float*)d_out;

    const int B = in_sizes[0] / (NUM_ENT * DIM_ENT);   // 16384
    const int nb = (B + BPB - 1) / BPB;                // 2048 blocks
    ace_kernel<<<nb, 256, 0, stream>>>(ctx, w_prop, b_prop, w_rel, b_rel, out, B);
}